// Round 3
// baseline (1277.800 us; speedup 1.0000x reference)
//
#include <hip/hip_runtime.h>
#include <hip/hip_bf16.h>

// DecodeLSTM: B=8192, T=1, H=1024, L=4.
// T=1 => per layer: x_t == h_prev_layer, so layers 1..3: z = h @ (Wx+Wh) + b.
// Layer 0: z = h0 @ Wh0 + x*Wx0(rank-1, epilogue) + b0.
// R3: containers are FP32 (holding bf16-rounded values). Convert to bf16 on
// the fly for MFMA. c carried fp32 in-place in d_out; h carried bf16 in ws.

#define MB_  8192
#define HB_  1024
#define KB_  1024

typedef __attribute__((ext_vector_type(8))) short bf16x8;
typedef __attribute__((ext_vector_type(4))) float f32x4;

__device__ __forceinline__ float sigmoidf_(float x) { return 1.0f / (1.0f + __expf(-x)); }
__device__ __forceinline__ float tanhf_fast(float x) { return 2.0f / (1.0f + __expf(-2.0f * x)) - 1.0f; }

__device__ __forceinline__ short f2bf(float f) {
  __hip_bfloat16 h = __float2bfloat16(f);
  return *(short*)&h;
}

// ---------------------------------------------------------------------------
// Weight prep: WT[L][n][k] bf16  (L=0: Wh0^T ; L>0: (Wx[L-1]+Wh[L-1])^T)
// Inputs fp32 (bf16-rounded values).
// ---------------------------------------------------------------------------
__global__ __launch_bounds__(256) void prep_weights(
    const float* __restrict__ Wh0,
    const float* __restrict__ Wx,
    const float* __restrict__ Wh,
    __hip_bfloat16* __restrict__ WT)
{
  __shared__ float t[32][33];
  const int L  = blockIdx.z;
  const int n0 = blockIdx.x * 32;
  const int k0 = blockIdx.y * 32;
  const int tx = threadIdx.x & 31;
  const int ty = threadIdx.x >> 5;   // 0..7
  if (L == 0) {
    for (int kk = ty; kk < 32; kk += 8)
      t[kk][tx] = Wh0[(size_t)(k0 + kk) * 4096 + n0 + tx];
  } else {
    const float* wx = Wx + (size_t)(L - 1) * 1024 * 4096;
    const float* wh = Wh + (size_t)(L - 1) * 1024 * 4096;
    for (int kk = ty; kk < 32; kk += 8) {
      size_t idx = (size_t)(k0 + kk) * 4096 + n0 + tx;
      t[kk][tx] = wx[idx] + wh[idx];
    }
  }
  __syncthreads();
  __hip_bfloat16* dst = WT + (size_t)L * 4096 * 1024;
  for (int nn = ty; nn < 32; nn += 8)
    dst[(size_t)(n0 + nn) * 1024 + k0 + tx] = __float2bfloat16(t[tx][nn]);
}

// ---------------------------------------------------------------------------
// Fused LSTM layer: z GEMM (MFMA 16x16x32 bf16) + gates + c/h update.
// Tile: 128 rows x 32 gate-cols (=128 z-cols), BK=64. 4 waves: 2x2.
// 4 gate-accumulators share each A fragment => all 4 gates of an element in
// the same lane/reg (C/D: col=lane&15, row=(lane>>4)*4+reg) -> in-reg epilogue.
// FIRST: A is fp32 (h0 input), layer-0 extras. LAST: h written fp32 to d_out.
// ---------------------------------------------------------------------------
template<bool FIRST, bool LAST>
__global__ __launch_bounds__(256) void lstm_layer_kernel(
    const void*           __restrict__ Ain,   // FIRST? fp32 [8192][1024] : bf16
    const __hip_bfloat16* __restrict__ WT,    // [4096][1024] bf16 (pre-summed)
    const float*          __restrict__ bias,  // [4096] fp32
    const float*                       cin,   // [8192][1024] fp32
    float*                             cout,  // may alias cin (same position)
    const float*          __restrict__ xvec,  // layer0 x [8192] fp32
    const float*          __restrict__ Wx0,   // layer0 [4096] fp32
    void*                 __restrict__ hout)  // LAST? fp32 : bf16
{
  __shared__ __align__(16) __hip_bfloat16 sA[8 * 128 * 8];  // [kc][m][8]  16 KB
  __shared__ __align__(16) __hip_bfloat16 sB[8 * 128 * 8];  // [kc][w][8]  16 KB

  const int tid  = threadIdx.x;
  const int lane = tid & 63;
  const int wv   = tid >> 6;          // 0..3
  const int m0   = blockIdx.y * 128;
  const int n0   = blockIdx.x * 32;   // gate-col base
  const int wm   = (wv & 1) * 64;
  const int wn   = (wv >> 1) * 16;

  const int l15 = lane & 15;
  const int lq  = lane >> 4;          // 0..3

  f32x4 acc[4][4] = {};               // [m-subtile][gate]

  for (int it = 0; it < 16; ++it) {
    const int k0 = it * 64;
    // ---- stage into registers ----
    bf16x8 ra[4];
    uint4  rb[4];
#pragma unroll
    for (int p = 0; p < 4; ++p) {
      const int t   = tid + p * 256;      // 0..1023
      const int row = t & 127;
      const int kc  = t >> 7;             // 0..7
      if (FIRST) {
        const float4* ap = (const float4*)((const float*)Ain +
                              (size_t)(m0 + row) * KB_ + k0 + kc * 8);
        const float4 f0 = ap[0];
        const float4 f1 = ap[1];
        bf16x8 v;
        v[0] = f2bf(f0.x); v[1] = f2bf(f0.y); v[2] = f2bf(f0.z); v[3] = f2bf(f0.w);
        v[4] = f2bf(f1.x); v[5] = f2bf(f1.y); v[6] = f2bf(f1.z); v[7] = f2bf(f1.w);
        ra[p] = v;
      } else {
        ra[p] = *(const bf16x8*)((const __hip_bfloat16*)Ain +
                              (size_t)(m0 + row) * KB_ + k0 + kc * 8);
      }
      // row enumerates z-cols: gate = row>>5, j = n0 + (row&31)
      const int grow = (row >> 5) * HB_ + n0 + (row & 31);
      rb[p] = *(const uint4*)(WT + (size_t)grow * KB_ + k0 + kc * 8);
    }
    __syncthreads();   // previous iteration's LDS readers done
#pragma unroll
    for (int p = 0; p < 4; ++p) {
      const int t   = tid + p * 256;
      const int row = t & 127;
      const int kc  = t >> 7;
      *(bf16x8*)&sA[(kc * 128 + row) * 8] = ra[p];
      *(uint4*)&sB[(kc * 128 + row) * 8] = rb[p];
    }
    __syncthreads();
    // ---- MFMA phase ----
#pragma unroll
    for (int ks = 0; ks < 2; ++ks) {
      const int kc = ks * 4 + lq;
      bf16x8 af[4];
#pragma unroll
      for (int s = 0; s < 4; ++s)
        af[s] = *(const bf16x8*)&sA[(kc * 128 + wm + s * 16 + l15) * 8];
      bf16x8 bfr[4];
#pragma unroll
      for (int g = 0; g < 4; ++g)
        bfr[g] = *(const bf16x8*)&sB[(kc * 128 + g * 32 + wn + l15) * 8];
#pragma unroll
      for (int s = 0; s < 4; ++s)
#pragma unroll
        for (int g = 0; g < 4; ++g)
          acc[s][g] = __builtin_amdgcn_mfma_f32_16x16x32_bf16(af[s], bfr[g], acc[s][g], 0, 0, 0);
    }
  }

  // Epilogue. C/D map: col = lane&15, row = (lane>>4)*4 + reg.
  const int jj = n0 + wn + l15;
  const float bi  = bias[0 * HB_ + jj];
  const float bf_ = bias[1 * HB_ + jj];
  const float bg  = bias[2 * HB_ + jj];
  const float bo  = bias[3 * HB_ + jj];
  float wxi = 0.f, wxf = 0.f, wxg = 0.f, wxo = 0.f;
  if (FIRST) {
    wxi = Wx0[0 * HB_ + jj];
    wxf = Wx0[1 * HB_ + jj];
    wxg = Wx0[2 * HB_ + jj];
    wxo = Wx0[3 * HB_ + jj];
  }
#pragma unroll
  for (int s = 0; s < 4; ++s) {
#pragma unroll
    for (int r = 0; r < 4; ++r) {
      const int m = m0 + wm + s * 16 + (lq << 2) + r;
      float zi = acc[s][0][r] + bi;
      float zf = acc[s][1][r] + bf_;
      float zg = acc[s][2][r] + bg;
      float zo = acc[s][3][r] + bo;
      if (FIRST) {
        const float xv = xvec[m];
        zi += xv * wxi; zf += xv * wxf; zg += xv * wxg; zo += xv * wxo;
      }
      const float ig = sigmoidf_(zi);
      const float fg = sigmoidf_(zf);
      const float gg = tanhf_fast(zg);
      const float og = sigmoidf_(zo);
      const size_t off = (size_t)m * HB_ + jj;
      const float cn = fg * cin[off] + ig * gg;
      const float hn = og * tanhf_fast(cn);
      cout[off] = cn;
      if (LAST) ((float*)hout)[off] = hn;
      else      ((__hip_bfloat16*)hout)[off] = __float2bfloat16(hn);
    }
  }
}

// ---------------------------------------------------------------------------
// Head: x_pred[b] = sum_k h4[b,k]*Wd[k] + bd.  One wave per row. All fp32.
// ---------------------------------------------------------------------------
__global__ __launch_bounds__(256) void head_kernel(
    const float* __restrict__ h,
    const float* __restrict__ Wd,
    const float* __restrict__ bd,
    float* __restrict__ xpred)
{
  const int row  = blockIdx.x * 4 + (threadIdx.x >> 6);
  const int lane = threadIdx.x & 63;
  const float* hr = h + (size_t)row * HB_;
  float s = 0.f;
#pragma unroll
  for (int t = 0; t < 16; ++t) {
    const int k = t * 64 + lane;
    s += hr[k] * Wd[k];
  }
#pragma unroll
  for (int off = 32; off; off >>= 1) s += __shfl_down(s, off, 64);
  if (lane == 0) xpred[row] = s + bd[0];
}

// ---------------------------------------------------------------------------
extern "C" void kernel_launch(void* const* d_in, const int* in_sizes, int n_in,
                              void* d_out, int out_size, void* d_ws, size_t ws_size,
                              hipStream_t stream) {
  (void)in_sizes; (void)n_in; (void)out_size; (void)ws_size;
  const float* x   = (const float*)d_in[0];
  const float* c0  = (const float*)d_in[1];
  const float* h0  = (const float*)d_in[2];
  const float* Wx0 = (const float*)d_in[3];
  const float* Wh0 = (const float*)d_in[4];
  const float* b0  = (const float*)d_in[5];
  const float* Wx  = (const float*)d_in[6];
  const float* Wh  = (const float*)d_in[7];
  const float* b   = (const float*)d_in[8];
  const float* Wd  = (const float*)d_in[9];
  const float* bd  = (const float*)d_in[10];

  float* out_c = (float*)d_out;
  float* out_h = out_c + (size_t)MB_ * HB_;
  float* out_x = out_h + (size_t)MB_ * HB_;

  char* ws = (char*)d_ws;
  __hip_bfloat16* WT = (__hip_bfloat16*)ws;                       // 32 MiB
  __hip_bfloat16* hA = (__hip_bfloat16*)(ws + (size_t)33554432);  // 16 MiB
  __hip_bfloat16* hB = (__hip_bfloat16*)(ws + (size_t)50331648);  // 16 MiB
  // total ws use: 64 MiB

  const size_t WTL = (size_t)4096 * 1024;

  prep_weights<<<dim3(128, 32, 4), 256, 0, stream>>>(Wh0, Wx, Wh, WT);

  dim3 grid(32, 64);  // n-tiles (H/32) x m-tiles (M/128)
  // L0: A=h0(fp32), c: c0 -> out_c ; h1 -> hA (bf16)
  lstm_layer_kernel<true,  false><<<grid, 256, 0, stream>>>(
      h0, WT, b0, c0, out_c, x, Wx0, hA);
  // L1: A=hA ; c in-place out_c ; h2 -> hB
  lstm_layer_kernel<false, false><<<grid, 256, 0, stream>>>(
      hA, WT + 1 * WTL, b + 0 * 4096, out_c, out_c, nullptr, nullptr, hB);
  // L2: A=hB ; c in-place ; h3 -> hA
  lstm_layer_kernel<false, false><<<grid, 256, 0, stream>>>(
      hB, WT + 2 * WTL, b + 1 * 4096, out_c, out_c, nullptr, nullptr, hA);
  // L3: A=hA ; c in-place (final) ; h4 -> out_h (fp32)
  lstm_layer_kernel<false, true><<<grid, 256, 0, stream>>>(
      hA, WT + 3 * WTL, b + 2 * 4096, out_c, out_c, nullptr, nullptr, out_h);

  head_kernel<<<2048, 256, 0, stream>>>(out_h, Wd, bd, out_x);
}

// Round 4
// 768.590 us; speedup vs baseline: 1.6625x; 1.6625x over previous
//
#include <hip/hip_runtime.h>
#include <hip/hip_bf16.h>

// DecodeLSTM: B=8192, T=1, H=1024, L=4.  fp32 containers (bf16-rounded values).
// T=1 => layers 1..3: z = h @ (Wx+Wh) + b ; layer 0: z = h0@Wh0 + x*Wx0 + b0.
// R4: m97-style global_load_lds(16B) staging + LDS-coalesced epilogue.

#define MB_  8192
#define HB_  1024
#define KB_  1024

typedef __attribute__((ext_vector_type(8))) short bf16x8;
typedef __attribute__((ext_vector_type(4))) float f32x4;

__device__ __forceinline__ void load_lds16(const void* g, void* l) {
  __builtin_amdgcn_global_load_lds(
      (const __attribute__((address_space(1))) unsigned int*)g,
      (__attribute__((address_space(3))) unsigned int*)l, 16, 0, 0);
}

__device__ __forceinline__ float sigmoidf_(float x) { return 1.0f / (1.0f + __expf(-x)); }
__device__ __forceinline__ float tanhf_fast(float x) { return 2.0f / (1.0f + __expf(-2.0f * x)) - 1.0f; }

__device__ __forceinline__ short f2bf(float f) {
  __hip_bfloat16 h = __float2bfloat16(f);
  return *(short*)&h;
}

// ---------------------------------------------------------------------------
// fp32 -> bf16 bulk convert (for h0). 8 elements/thread.
// ---------------------------------------------------------------------------
__global__ __launch_bounds__(256) void cvt_f32_bf16(
    const float* __restrict__ in, __hip_bfloat16* __restrict__ out)
{
  const int i = blockIdx.x * 256 + threadIdx.x;
  const float4 f0 = ((const float4*)in)[i * 2];
  const float4 f1 = ((const float4*)in)[i * 2 + 1];
  bf16x8 v;
  v[0] = f2bf(f0.x); v[1] = f2bf(f0.y); v[2] = f2bf(f0.z); v[3] = f2bf(f0.w);
  v[4] = f2bf(f1.x); v[5] = f2bf(f1.y); v[6] = f2bf(f1.z); v[7] = f2bf(f1.w);
  ((bf16x8*)out)[i] = v;
}

// ---------------------------------------------------------------------------
// Weight prep: WT[L][n][k] bf16  (L=0: Wh0^T ; L>0: (Wx[L-1]+Wh[L-1])^T)
// ---------------------------------------------------------------------------
__global__ __launch_bounds__(256) void prep_weights(
    const float* __restrict__ Wh0,
    const float* __restrict__ Wx,
    const float* __restrict__ Wh,
    __hip_bfloat16* __restrict__ WT)
{
  __shared__ float t[32][33];
  const int L  = blockIdx.z;
  const int n0 = blockIdx.x * 32;
  const int k0 = blockIdx.y * 32;
  const int tx = threadIdx.x & 31;
  const int ty = threadIdx.x >> 5;   // 0..7
  if (L == 0) {
    for (int kk = ty; kk < 32; kk += 8)
      t[kk][tx] = Wh0[(size_t)(k0 + kk) * 4096 + n0 + tx];
  } else {
    const float* wx = Wx + (size_t)(L - 1) * 1024 * 4096;
    const float* wh = Wh + (size_t)(L - 1) * 1024 * 4096;
    for (int kk = ty; kk < 32; kk += 8) {
      size_t idx = (size_t)(k0 + kk) * 4096 + n0 + tx;
      t[kk][tx] = wx[idx] + wh[idx];
    }
  }
  __syncthreads();
  __hip_bfloat16* dst = WT + (size_t)L * 4096 * 1024;
  for (int nn = ty; nn < 32; nn += 8)
    dst[(size_t)(n0 + nn) * 1024 + k0 + tx] = __float2bfloat16(t[tx][nn]);
}

// ---------------------------------------------------------------------------
// Fused LSTM layer. Tile: 128 rows x 32 h-cols (=128 z-cols), BK=64, 4 waves.
// K-loop: 2-barrier global_load_lds staging (m97 structure).
// Epilogue: cin tile -> LDS (async, coalesced), gate math vs LDS, c/h tiles
// back through LDS, coalesced stores.
// C/D map: col=lane&15, row=(lane>>4)*4+reg.
// ---------------------------------------------------------------------------
template<bool FIRST, bool LAST>
__global__ __launch_bounds__(256) void lstm_layer_kernel(
    const __hip_bfloat16* __restrict__ A,     // [8192][1024] bf16
    const __hip_bfloat16* __restrict__ WT,    // [4096][1024] bf16 (pre-summed)
    const float*          __restrict__ bias,  // [4096] fp32
    const float*                       cin,   // [8192][1024] fp32
    float*                             cout,  // may alias cin (same positions)
    const float*          __restrict__ xvec,  // layer0 x [8192] fp32
    const float*          __restrict__ Wx0,   // layer0 [4096] fp32
    void*                 __restrict__ hout)  // LAST? fp32 : bf16
{
  __shared__ __align__(16) __hip_bfloat16 sA[8 * 128 * 8];  // [kc][m][8] 16 KB
  __shared__ __align__(16) __hip_bfloat16 sB[8 * 128 * 8];  // [kc][w][8] 16 KB

  const int tid  = threadIdx.x;
  const int lane = tid & 63;
  const int wv   = tid >> 6;          // 0..3
  const int m0   = blockIdx.y * 128;
  const int n0   = blockIdx.x * 32;   // h-col base
  const int wm   = (wv & 1) * 64;
  const int wn   = (wv >> 1) * 16;

  const int l15 = lane & 15;
  const int lq  = lane >> 4;          // 0..3

  f32x4 acc[4][4] = {};               // [m-subtile][gate]

  for (int it = 0; it < 16; ++it) {
    const int k0 = it * 64;
    __syncthreads();                  // prev iteration's LDS readers done
#pragma unroll
    for (int q = 0; q < 4; ++q) {
      const int i  = wv * 4 + q;      // 0..15
      const int kc = i >> 1, mb = i & 1;
      load_lds16(A + (size_t)(m0 + mb * 64 + lane) * KB_ + k0 + kc * 8,
                 &sA[(kc * 128 + mb * 64) * 8]);
      const int w    = mb * 64 + lane;          // z-col index 0..127
      const int grow = (w >> 5) * HB_ + n0 + (w & 31);
      load_lds16(WT + (size_t)grow * KB_ + k0 + kc * 8,
                 &sB[(kc * 128 + mb * 64) * 8]);
    }
    __syncthreads();                  // drains vmcnt(0): tiles in LDS
#pragma unroll
    for (int ks = 0; ks < 2; ++ks) {
      const int kc = ks * 4 + lq;
      bf16x8 af[4];
#pragma unroll
      for (int s = 0; s < 4; ++s)
        af[s] = *(const bf16x8*)&sA[(kc * 128 + wm + s * 16 + l15) * 8];
      bf16x8 bfr[4];
#pragma unroll
      for (int g = 0; g < 4; ++g)
        bfr[g] = *(const bf16x8*)&sB[(kc * 128 + g * 32 + wn + l15) * 8];
#pragma unroll
      for (int s = 0; s < 4; ++s)
#pragma unroll
        for (int g = 0; g < 4; ++g)
          acc[s][g] = __builtin_amdgcn_mfma_f32_16x16x32_bf16(af[s], bfr[g], acc[s][g], 0, 0, 0);
    }
  }

  // ---- epilogue ----
  __syncthreads();                    // all MFMA LDS reads done; sA/sB free
  float* sC = (float*)sA;             // [128][32] fp32 c tile  (16 KB)
  float* sH = (float*)sB;             // [128][32] fp32 h tile  (16 KB)

  // cin tile (rows m0..+127, cols n0..+31) -> sC, coalesced async
#pragma unroll
  for (int q = 0; q < 4; ++q) {
    const int i    = wv * 4 + q;                // 0..15, 8 rows each
    const int rowg = m0 + i * 8 + (lane >> 3);
    const int colg = n0 + (lane & 7) * 4;
    load_lds16(cin + (size_t)rowg * HB_ + colg, &sC[i * 8 * 32]);
  }

  const int jj = n0 + wn + l15;
  const float bi  = bias[0 * HB_ + jj];
  const float bf_ = bias[1 * HB_ + jj];
  const float bg  = bias[2 * HB_ + jj];
  const float bo  = bias[3 * HB_ + jj];
  float wxi = 0.f, wxf = 0.f, wxg = 0.f, wxo = 0.f;
  if (FIRST) {
    wxi = Wx0[0 * HB_ + jj];
    wxf = Wx0[1 * HB_ + jj];
    wxg = Wx0[2 * HB_ + jj];
    wxo = Wx0[3 * HB_ + jj];
  }
  __syncthreads();                    // cin tile landed

  const int colL = wn + l15;          // local col 0..31
#pragma unroll
  for (int s = 0; s < 4; ++s) {
#pragma unroll
    for (int r = 0; r < 4; ++r) {
      const int mloc = wm + s * 16 + (lq << 2) + r;   // local row 0..127
      float zi = acc[s][0][r] + bi;
      float zf = acc[s][1][r] + bf_;
      float zg = acc[s][2][r] + bg;
      float zo = acc[s][3][r] + bo;
      if (FIRST) {
        const float xv = xvec[m0 + mloc];
        zi += xv * wxi; zf += xv * wxf; zg += xv * wxg; zo += xv * wxo;
      }
      const float ig = sigmoidf_(zi);
      const float fg = sigmoidf_(zf);
      const float gg = tanhf_fast(zg);
      const float og = sigmoidf_(zo);
      const float cn = fg * sC[mloc * 32 + colL] + ig * gg;  // in-place safe:
      const float hn = og * tanhf_fast(cn);                  // 1 owner per elem
      sC[mloc * 32 + colL] = cn;
      sH[mloc * 32 + colL] = hn;
    }
  }
  __syncthreads();                    // c/h tiles complete

  // coalesced stores: c (fp32) 128x32 -> 1024 float4, 4 passes
#pragma unroll
  for (int p = 0; p < 4; ++p) {
    const int idx = p * 256 + tid;
    const int row = idx >> 3, seg = idx & 7;
    *(float4*)(cout + (size_t)(m0 + row) * HB_ + n0 + seg * 4) =
        *(const float4*)&sC[row * 32 + seg * 4];
  }
  if (LAST) {
#pragma unroll
    for (int p = 0; p < 4; ++p) {
      const int idx = p * 256 + tid;
      const int row = idx >> 3, seg = idx & 7;
      *(float4*)((float*)hout + (size_t)(m0 + row) * HB_ + n0 + seg * 4) =
          *(const float4*)&sH[row * 32 + seg * 4];
    }
  } else {
#pragma unroll
    for (int p = 0; p < 2; ++p) {
      const int idx = p * 256 + tid;
      const int row = idx >> 2, seg = idx & 3;          // 8 bf16 per thread
      const float4 f0 = *(const float4*)&sH[row * 32 + seg * 8];
      const float4 f1 = *(const float4*)&sH[row * 32 + seg * 8 + 4];
      bf16x8 v;
      v[0] = f2bf(f0.x); v[1] = f2bf(f0.y); v[2] = f2bf(f0.z); v[3] = f2bf(f0.w);
      v[4] = f2bf(f1.x); v[5] = f2bf(f1.y); v[6] = f2bf(f1.z); v[7] = f2bf(f1.w);
      *(bf16x8*)((__hip_bfloat16*)hout + (size_t)(m0 + row) * HB_ + n0 + seg * 8) = v;
    }
  }
}

// ---------------------------------------------------------------------------
// Head: x_pred[b] = sum_k h4[b,k]*Wd[k] + bd.  One wave per row. All fp32.
// ---------------------------------------------------------------------------
__global__ __launch_bounds__(256) void head_kernel(
    const float* __restrict__ h,
    const float* __restrict__ Wd,
    const float* __restrict__ bd,
    float* __restrict__ xpred)
{
  const int row  = blockIdx.x * 4 + (threadIdx.x >> 6);
  const int lane = threadIdx.x & 63;
  const float* hr = h + (size_t)row * HB_;
  float s = 0.f;
#pragma unroll
  for (int t = 0; t < 16; ++t) {
    const int k = t * 64 + lane;
    s += hr[k] * Wd[k];
  }
#pragma unroll
  for (int off = 32; off; off >>= 1) s += __shfl_down(s, off, 64);
  if (lane == 0) xpred[row] = s + bd[0];
}

// ---------------------------------------------------------------------------
extern "C" void kernel_launch(void* const* d_in, const int* in_sizes, int n_in,
                              void* d_out, int out_size, void* d_ws, size_t ws_size,
                              hipStream_t stream) {
  (void)in_sizes; (void)n_in; (void)out_size; (void)ws_size;
  const float* x   = (const float*)d_in[0];
  const float* c0  = (const float*)d_in[1];
  const float* h0  = (const float*)d_in[2];
  const float* Wx0 = (const float*)d_in[3];
  const float* Wh0 = (const float*)d_in[4];
  const float* b0  = (const float*)d_in[5];
  const float* Wx  = (const float*)d_in[6];
  const float* Wh  = (const float*)d_in[7];
  const float* b   = (const float*)d_in[8];
  const float* Wd  = (const float*)d_in[9];
  const float* bd  = (const float*)d_in[10];

  float* out_c = (float*)d_out;
  float* out_h = out_c + (size_t)MB_ * HB_;
  float* out_x = out_h + (size_t)MB_ * HB_;

  char* ws = (char*)d_ws;
  __hip_bfloat16* WT = (__hip_bfloat16*)ws;                       // 32 MiB
  __hip_bfloat16* hA = (__hip_bfloat16*)(ws + (size_t)33554432);  // 16 MiB
  __hip_bfloat16* hB = (__hip_bfloat16*)(ws + (size_t)50331648);  // 16 MiB

  const size_t WTL = (size_t)4096 * 1024;

  prep_weights<<<dim3(128, 32, 4), 256, 0, stream>>>(Wh0, Wx, Wh, WT);
  cvt_f32_bf16<<<4096, 256, 0, stream>>>(h0, hA);   // h0 -> bf16 (exact)

  dim3 grid(32, 64);  // n-tiles (H/32) x m-tiles (M/128)
  // L0: A=hA(h0 bf16), c: c0 -> out_c ; h1 -> hB
  lstm_layer_kernel<true,  false><<<grid, 256, 0, stream>>>(
      hA, WT, b0, c0, out_c, x, Wx0, hB);
  // L1: A=hB ; c in-place out_c ; h2 -> hA
  lstm_layer_kernel<false, false><<<grid, 256, 0, stream>>>(
      hB, WT + 1 * WTL, b + 0 * 4096, out_c, out_c, nullptr, nullptr, hA);
  // L2: A=hA ; c in-place ; h3 -> hB
  lstm_layer_kernel<false, false><<<grid, 256, 0, stream>>>(
      hA, WT + 2 * WTL, b + 1 * 4096, out_c, out_c, nullptr, nullptr, hB);
  // L3: A=hB ; c in-place (final) ; h4 -> out_h (fp32)
  lstm_layer_kernel<false, true><<<grid, 256, 0, stream>>>(
      hB, WT + 3 * WTL, b + 2 * 4096, out_c, out_c, nullptr, nullptr, out_h);

  head_kernel<<<2048, 256, 0, stream>>>(out_h, Wd, bd, out_x);
}